// Round 7
// baseline (324.845 us; speedup 1.0000x reference)
//
#include <hip/hip_runtime.h>
#include <math.h>

typedef unsigned short u16;
typedef __attribute__((ext_vector_type(8))) short short8;   // 8 bf16 = 4 VGPRs
typedef __attribute__((ext_vector_type(4))) float floatx4;  // MFMA 16x16 C/D

// fp32 -> bf16 round-to-nearest-even
__device__ __forceinline__ u16 f2bf(float f) {
  union { float f; unsigned u; } v; v.f = f;
  unsigned r = (v.u + 0x7FFFu + ((v.u >> 16) & 1u)) >> 16;
  return (u16)r;
}

// async global->LDS, 16B per lane; LDS dest must be wave-uniform base + lane*16
#define GLD16(gp, lp) __builtin_amdgcn_global_load_lds(                      \
    (__attribute__((address_space(1))) void*)(gp),                           \
    (__attribute__((address_space(3))) void*)(lp), 16, 0, 0)

// ---------------------------------------------------------------------------
// f32 -> bf16 conversion: 5 tensors of 4194304 elements each, contiguous dst.
// ---------------------------------------------------------------------------
__global__ __launch_bounds__(256) void cvt_all(
    const float* __restrict__ H, const float* __restrict__ Wq,
    const float* __restrict__ Wk, const float* __restrict__ Wv,
    const float* __restrict__ Wo, u16* __restrict__ dst) {
  const float* srcs[5] = {H, Wq, Wk, Wv, Wo};
  const int sel = blockIdx.y;
  const float* s = srcs[sel];
  u16* d = dst + (size_t)sel * 4194304;
  const int idx = (blockIdx.x * 256 + threadIdx.x) * 4;
  const float4 v = *(const float4*)(s + idx);
  ushort4 o;
  o.x = f2bf(v.x); o.y = f2bf(v.y); o.z = f2bf(v.z); o.w = f2bf(v.w);
  *(ushort4*)(d + idx) = o;
}

// ---------------------------------------------------------------------------
// GEMM core: C[m,n] = sum_k A[m,k] * B[n,k]  (B^T layout, all dims 2048)
// 128x128 tile, BK=64, 4 waves each computing 64x64 (4x4 MFMA tiles).
// XOR column-chunk swizzle breaks the 16-way LDS bank conflict (R6: 39%->win).
// mode 0: C row-major fp32; mode 1: head-split bf16 [bh,1024,64];
// mode 2: head-split-T bf16 [bh,64,1024].
// ---------------------------------------------------------------------------
__device__ __forceinline__ void gemm_core(const u16* __restrict__ A,
                                          const u16* __restrict__ B,
                                          u16* __restrict__ Cb,
                                          float* __restrict__ Cf,
                                          int M0, int N0, int mode, float cscale,
                                          u16* lA, u16* lB) {
  const int tid = threadIdx.x;
  const int lane = tid & 63;
  const int wave = tid >> 6;
  const int lq = lane & 15, quad = lane >> 4;
  const int wm = wave & 1, wn = wave >> 1;

  floatx4 acc[4][4];
#pragma unroll
  for (int i = 0; i < 4; ++i)
#pragma unroll
    for (int j = 0; j < 4; ++j) acc[i][j] = (floatx4)0.f;

  const int srow = tid >> 3;        // 0..31
  const int cc = tid & 7;           // column chunk 0..7

  for (int k0 = 0; k0 < 2048; k0 += 64) {
    __syncthreads();
#pragma unroll
    for (int r = 0; r < 4; ++r) {
      const int row = r * 32 + srow;
      const int gcol = ((cc ^ (row & 7)) << 3);   // swizzled global chunk
      const int flat = row * 64 + (cc << 3);      // contiguous LDS dest
      GLD16(A + (size_t)(M0 + row) * 2048 + k0 + gcol, lA + flat);
      GLD16(B + (size_t)(N0 + row) * 2048 + k0 + gcol, lB + flat);
    }
    __syncthreads();
    const int sw = lq & 7;
#pragma unroll
    for (int ks8 = 0; ks8 < 8; ks8 += 4) {        // ks = ks8*8 in {0,32}
      short8 af[4], bf[4];
#pragma unroll
      for (int t = 0; t < 4; ++t)
        af[t] = *(const short8*)&lA[(wm * 64 + t * 16 + lq) * 64 + (((quad + ks8) ^ sw) << 3)];
#pragma unroll
      for (int t = 0; t < 4; ++t)
        bf[t] = *(const short8*)&lB[(wn * 64 + t * 16 + lq) * 64 + (((quad + ks8) ^ sw) << 3)];
#pragma unroll
      for (int i = 0; i < 4; ++i)
#pragma unroll
        for (int j = 0; j < 4; ++j)
          acc[i][j] = __builtin_amdgcn_mfma_f32_16x16x32_bf16(af[i], bf[j], acc[i][j], 0, 0, 0);
    }
  }

  // epilogue: C/D layout col=lane&15, row=quad*4+reg
#pragma unroll
  for (int i = 0; i < 4; ++i)
#pragma unroll
    for (int j = 0; j < 4; ++j)
#pragma unroll
      for (int r = 0; r < 4; ++r) {
        const int m = M0 + wm * 64 + i * 16 + quad * 4 + r;
        const int n = N0 + wn * 64 + j * 16 + lq;
        if (mode == 0) {
          Cf[(size_t)m * 2048 + n] = acc[i][j][r];
        } else {
          const int bh = ((m >> 10) << 5) | (n >> 6);  // b*32 + head
          size_t addr;
          if (mode == 1) addr = ((size_t)bh * 1024 + (m & 1023)) * 64 + (n & 63);
          else           addr = ((size_t)bh * 64 + (n & 63)) * 1024 + (m & 1023);
          Cb[addr] = f2bf(acc[i][j][r] * cscale);
        }
      }
}

__global__ __launch_bounds__(256, 3) void gemm_qkv(
    const u16* __restrict__ H,
    const u16* __restrict__ Wq, const u16* __restrict__ Wk, const u16* __restrict__ Wv,
    u16* __restrict__ q, u16* __restrict__ k, u16* __restrict__ vt) {
  __shared__ __align__(16) u16 lA[128 * 64];
  __shared__ __align__(16) u16 lB[128 * 64];
  const int M0 = blockIdx.x * 128;
  const int sel = blockIdx.y >> 4;        // 0:Q 1:K 2:V
  const int N0 = (blockIdx.y & 15) * 128;
  const u16* B = (sel == 0) ? Wq : (sel == 1) ? Wk : Wv;
  u16* C = (sel == 0) ? q : (sel == 1) ? k : vt;
  gemm_core(H, B, C, nullptr, M0, N0, (sel == 2) ? 2 : 1,
            (sel == 0) ? 0.125f : 1.f, lA, lB);
}

__global__ __launch_bounds__(256, 3) void gemm_out(
    const u16* __restrict__ A, const u16* __restrict__ W, float* __restrict__ C) {
  __shared__ __align__(16) u16 lA[128 * 64];
  __shared__ __align__(16) u16 lB[128 * 64];
  gemm_core(A, W, nullptr, C, blockIdx.x * 128, blockIdx.y * 128, 0, 1.f, lA, lB);
}

// ---------------------------------------------------------------------------
// Stick-breaking attention, multiplicative form, transposed z, PIPELINED:
//   p = sigmoid(z), att[i,j] = p(i,j) * prod_{j<k<i} (1 - p(i,k))
// Tile-local P (carry factored OUT): O += carry * (P_loc V); carry *= tile_tot.
// -> tiles data-independent except a 20-cycle f32 epilogue; K prefetched one
// tile ahead (2 reg sets); parallel (not chained) cross-quad gathers for the
// suffix products; double-buffered P slab.
// ---------------------------------------------------------------------------
#define PSTR 72  // P slab row stride in u16 (64 + 8 pad; rows 144B, 16B-aligned)
#define PBUF (16 * PSTR)

__device__ __forceinline__ void load_k(const u16* __restrict__ kb0, int j0,
                                       int lq, int quad,
                                       short8 (&kf0)[4], short8 (&kf1)[4]) {
#pragma unroll
  for (int c = 0; c < 4; ++c) {
    const u16* kr = &kb0[(size_t)(j0 + 16 * c + lq) * 64 + quad * 8];
    kf0[c] = *(const short8*)kr;
    kf1[c] = *(const short8*)(kr + 32);
  }
}

template <bool MASKED>
__device__ __forceinline__ void sba_tile(
    int j0, int q0, int lq, int quad,
    const short8 (&kf0)[4], const short8 (&kf1)[4],
    const u16* __restrict__ vb, u16* pw,
    const short8& qf0, const short8& qf1,
    floatx4 (&o)[4], float& carry) {
  // V loads at body top (consumed ~400 cycles later, after the LDS barrier)
  short8 vfA[4], vfB[4];
#pragma unroll
  for (int tt = 0; tt < 4; ++tt) {
    const u16* vr = &vb[(size_t)(tt * 16 + lq) * 1024 + j0 + quad * 8];
    vfA[tt] = *(const short8*)vr;
    vfB[tt] = *(const short8*)(vr + 32);
  }
  floatx4 zc[4];
#pragma unroll
  for (int c = 0; c < 4; ++c) {
    floatx4 z = (floatx4)0.f;
    z = __builtin_amdgcn_mfma_f32_16x16x32_bf16(kf0[c], qf0, z, 0, 0, 0);
    z = __builtin_amdgcn_mfma_f32_16x16x32_bf16(kf1[c], qf1, z, 0, 0, 0);
    zc[c] = z;
  }
  // per-chunk: pe_r = p_r * (suffix of g within quad), qt = quad product of g
  float pe0[4], pe1[4], pe2[4], pe3[4], qt[4];
#pragma unroll
  for (int c = 0; c < 4; ++c) {
    float p[4], g[4];
#pragma unroll
    for (int r = 0; r < 4; ++r) {
      const float z = zc[c][r];
      const float e = __expf(-z);
      float pp = __builtin_amdgcn_rcpf(1.f + e);   // sigmoid
      float gg = e * pp;                            // 1 - sigmoid
      if (MASKED) {
        const bool valid = (j0 + 16 * c + quad * 4 + r) < (q0 + lq);
        gg = valid ? gg : 1.f;
        pp = valid ? pp : 0.f;
      }
      p[r] = pp; g[r] = gg;
    }
    const float er2 = g[3];
    const float er1 = er2 * g[2];
    const float er0 = er1 * g[1];
    qt[c] = er0 * g[0];
    pe0[c] = p[0] * er0; pe1[c] = p[1] * er1; pe2[c] = p[2] * er2; pe3[c] = p[3];
  }
  // 16 INDEPENDENT cross-quad gathers (no chained scan)
  float s0[4], s1[4], s2[4], s3[4];
#pragma unroll
  for (int c = 0; c < 4; ++c) {
    s0[c] = __shfl(qt[c], lq);
    s1[c] = __shfl(qt[c], lq + 16);
    s2[c] = __shfl(qt[c], lq + 32);
    s3[c] = __shfl(qt[c], lq + 48);
  }
  float tot[4], Qs[4];
#pragma unroll
  for (int c = 0; c < 4; ++c) {
    const float a = (quad < 1) ? s1[c] : 1.f;
    const float b = (quad < 2) ? s2[c] : 1.f;
    const float d = (quad < 3) ? s3[c] : 1.f;
    Qs[c] = a * b * d;                       // exclusive quad-suffix
    tot[c] = s0[c] * s1[c] * s2[c] * s3[c];  // chunk total
  }
  const float suf2 = tot[3];
  const float suf1 = tot[3] * tot[2];
  const float suf0 = suf1 * tot[1];
  const float tile_tot = suf0 * tot[0];
  const float QF0 = Qs[0] * suf0, QF1 = Qs[1] * suf1;
  const float QF2 = Qs[2] * suf2, QF3 = Qs[3];
  const float QF[4] = {QF0, QF1, QF2, QF3};
#pragma unroll
  for (int c = 0; c < 4; ++c) {
    ushort4 pk;
    pk.x = f2bf(pe0[c] * QF[c]);
    pk.y = f2bf(pe1[c] * QF[c]);
    pk.z = f2bf(pe2[c] * QF[c]);
    pk.w = f2bf(pe3[c] * QF[c]);
    *(ushort4*)&pw[lq * PSTR + c * 16 + quad * 4] = pk;  // [query][key]
  }
  __asm__ volatile("s_waitcnt lgkmcnt(0)" ::: "memory");  // P visible to own wave
  const short8 pA = *(const short8*)&pw[lq * PSTR + quad * 8];
  const short8 pB = *(const short8*)&pw[lq * PSTR + 32 + quad * 8];
  floatx4 ot[4];
#pragma unroll
  for (int tt = 0; tt < 4; ++tt) ot[tt] = (floatx4)0.f;
#pragma unroll
  for (int tt = 0; tt < 4; ++tt) {
    ot[tt] = __builtin_amdgcn_mfma_f32_16x16x32_bf16(vfA[tt], pA, ot[tt], 0, 0, 0);
    ot[tt] = __builtin_amdgcn_mfma_f32_16x16x32_bf16(vfB[tt], pB, ot[tt], 0, 0, 0);
  }
#pragma unroll
  for (int tt = 0; tt < 4; ++tt)
#pragma unroll
    for (int r = 0; r < 4; ++r)
      o[tt][r] = fmaf(carry, ot[tt][r], o[tt][r]);
  carry *= tile_tot;
}

__global__ __launch_bounds__(256, 3) void sba_attn(
    const u16* __restrict__ Q, const u16* __restrict__ Km,
    const u16* __restrict__ Vt, u16* __restrict__ AO) {
  __shared__ __align__(16) u16 lP[4][2 * PBUF];  // per-wave double-buffered slab
  const int tid = threadIdx.x;
  const int lane = tid & 63;
  const int wave = tid >> 6;
  const int lq = lane & 15, quad = lane >> 4;
  // XCD-affinity swizzle: all 16 blocks of one head land on one XCD
  const int blk = blockIdx.x;
  const int xcd = blk & 7, y = blk >> 3;
  const int bh = xcd + 8 * (y >> 4);
  const int u = (y & 15) * 4 + wave;
  const int t = (u & 1) ? (63 - (u >> 1)) : (u >> 1);  // balance: pair t with 63-t
  const int q0 = t << 4;

  // Q B-frags (pre-scaled by 1/8 in gemm_qkv)
  const u16* qb = Q + ((size_t)bh * 1024 + q0) * 64;
  const short8 qf0 = *(const short8*)&qb[lq * 64 + quad * 8];
  const short8 qf1 = *(const short8*)&qb[lq * 64 + 32 + quad * 8];

  const u16* kb0 = Km + (size_t)bh * 65536;
  const u16* vb  = Vt + (size_t)bh * 65536;

  floatx4 o[4];
#pragma unroll
  for (int tt = 0; tt < 4; ++tt) o[tt] = (floatx4)0.f;
  float carry = 1.f;
  u16* pws = &lP[wave][0];

  int j0 = q0 & ~63;  // 64-aligned diagonal tile
  short8 kA0[4], kA1[4], kB0[4], kB1[4];
  load_k(kb0, j0, lq, quad, kA0, kA1);
  if (j0 >= 64) load_k(kb0, j0 - 64, lq, quad, kB0, kB1);
  sba_tile<true>(j0, q0, lq, quad, kA0, kA1, vb, pws, qf0, qf1, o, carry);
  j0 -= 64;
  int ph = 1;
  while (j0 >= 0) {
    if (j0 >= 64) load_k(kb0, j0 - 64, lq, quad, kA0, kA1);  // prefetch n+1
    sba_tile<false>(j0, q0, lq, quad, kB0, kB1, vb, pws + ph * PBUF, qf0, qf1, o, carry);
    j0 -= 64; ph ^= 1;
    if (j0 < 0) break;
    if (j0 >= 64) load_k(kb0, j0 - 64, lq, quad, kB0, kB1);  // prefetch n+1
    sba_tile<false>(j0, q0, lq, quad, kA0, kA1, vb, pws + ph * PBUF, qf0, qf1, o, carry);
    j0 -= 64; ph ^= 1;
  }

  // O^T (d=tt*16+quad*4+r, query=lq) -> LDS [query][d] -> coalesced 16B stores
#pragma unroll
  for (int tt = 0; tt < 4; ++tt) {
    ushort4 pk;
    pk.x = f2bf(o[tt][0]); pk.y = f2bf(o[tt][1]);
    pk.z = f2bf(o[tt][2]); pk.w = f2bf(o[tt][3]);
    *(ushort4*)&pws[lq * PSTR + tt * 16 + quad * 4] = pk;
  }
  __asm__ volatile("s_waitcnt lgkmcnt(0)" ::: "memory");
  const int b = bh >> 5, hd = bh & 31;
#pragma unroll
  for (int ps = 0; ps < 2; ++ps) {
    const int row = lane >> 2;
    const int colu = ((lane & 3) + 4 * ps) * 8;
    const short8 val = *(const short8*)&pws[row * PSTR + colu];
    *(short8*)&AO[((size_t)b * 1024 + q0 + row) * 2048 + hd * 64 + colu] = val;
  }
}

extern "C" void kernel_launch(void* const* d_in, const int* in_sizes, int n_in,
                              void* d_out, int out_size, void* d_ws, size_t ws_size,
                              hipStream_t stream) {
  const float* H  = (const float*)d_in[0];
  const float* Wq = (const float*)d_in[1];
  const float* Wk = (const float*)d_in[2];
  const float* Wv = (const float*)d_in[3];
  const float* Wo = (const float*)d_in[4];

  u16* ws = (u16*)d_ws;
  u16* Hb  = ws;                  // [2048,2048] 8MB  (reused as ao after gemm_qkv)
  u16* Wqb = ws + 1 * 4194304;
  u16* Wkb = ws + 2 * 4194304;
  u16* Wvb = ws + 3 * 4194304;
  u16* Wob = ws + 4 * 4194304;
  u16* q   = ws + 5 * 4194304;    // [64,1024,64], pre-scaled by 1/8
  u16* k   = ws + 6 * 4194304;
  u16* vt  = ws + 7 * 4194304;    // [64,64,1024]
  u16* ao  = Hb;                  // alias: H consumed by gemm_qkv before sba_attn writes

  dim3 gc(4096, 5);
  cvt_all<<<gc, 256, 0, stream>>>(H, Wq, Wk, Wv, Wo, ws);

  dim3 gq(16, 48);
  gemm_qkv<<<gq, 256, 0, stream>>>(Hb, Wqb, Wkb, Wvb, q, k, vt);
  sba_attn<<<1024, 256, 0, stream>>>(q, k, vt, ao);
  dim3 go(16, 16);
  gemm_out<<<go, 256, 0, stream>>>(ao, Wob, (float*)d_out);
}

// Round 8
// 296.899 us; speedup vs baseline: 1.0941x; 1.0941x over previous
//
#include <hip/hip_runtime.h>
#include <math.h>

typedef unsigned short u16;
typedef __attribute__((ext_vector_type(8))) short short8;   // 8 bf16 = 4 VGPRs
typedef __attribute__((ext_vector_type(4))) float floatx4;  // MFMA 16x16 C/D

// fp32 -> bf16 round-to-nearest-even
__device__ __forceinline__ u16 f2bf(float f) {
  union { float f; unsigned u; } v; v.f = f;
  unsigned r = (v.u + 0x7FFFu + ((v.u >> 16) & 1u)) >> 16;
  return (u16)r;
}

// async global->LDS, 16B per lane; LDS dest must be wave-uniform base + lane*16
#define GLD16(gp, lp) __builtin_amdgcn_global_load_lds(                      \
    (__attribute__((address_space(1))) void*)(gp),                           \
    (__attribute__((address_space(3))) void*)(lp), 16, 0, 0)

// ---------------------------------------------------------------------------
// f32 -> bf16 conversion: 5 tensors of 4194304 elements each, contiguous dst.
// ---------------------------------------------------------------------------
__global__ __launch_bounds__(256) void cvt_all(
    const float* __restrict__ H, const float* __restrict__ Wq,
    const float* __restrict__ Wk, const float* __restrict__ Wv,
    const float* __restrict__ Wo, u16* __restrict__ dst) {
  const float* srcs[5] = {H, Wq, Wk, Wv, Wo};
  const int sel = blockIdx.y;
  const float* s = srcs[sel];
  u16* d = dst + (size_t)sel * 4194304;
  const int idx = (blockIdx.x * 256 + threadIdx.x) * 4;
  const float4 v = *(const float4*)(s + idx);
  ushort4 o;
  o.x = f2bf(v.x); o.y = f2bf(v.y); o.z = f2bf(v.z); o.w = f2bf(v.w);
  *(ushort4*)(d + idx) = o;
}

// ---------------------------------------------------------------------------
// GEMM core: C[m,n] = sum_k A[m,k] * B[n,k]  (B^T layout, all dims 2048)
// 128x128 tile, BK=64, 4 waves each computing 64x64 (4x4 MFMA tiles).
// XOR column-chunk swizzle breaks the 16-way LDS bank conflict (R6 win).
// ---------------------------------------------------------------------------
__device__ __forceinline__ void gemm_core(const u16* __restrict__ A,
                                          const u16* __restrict__ B,
                                          u16* __restrict__ Cb,
                                          float* __restrict__ Cf,
                                          int M0, int N0, int mode, float cscale,
                                          u16* lA, u16* lB) {
  const int tid = threadIdx.x;
  const int lane = tid & 63;
  const int wave = tid >> 6;
  const int lq = lane & 15, quad = lane >> 4;
  const int wm = wave & 1, wn = wave >> 1;

  floatx4 acc[4][4];
#pragma unroll
  for (int i = 0; i < 4; ++i)
#pragma unroll
    for (int j = 0; j < 4; ++j) acc[i][j] = (floatx4)0.f;

  const int srow = tid >> 3;        // 0..31
  const int cc = tid & 7;           // column chunk 0..7

  for (int k0 = 0; k0 < 2048; k0 += 64) {
    __syncthreads();
#pragma unroll
    for (int r = 0; r < 4; ++r) {
      const int row = r * 32 + srow;
      const int gcol = ((cc ^ (row & 7)) << 3);   // swizzled global chunk
      const int flat = row * 64 + (cc << 3);      // contiguous LDS dest
      GLD16(A + (size_t)(M0 + row) * 2048 + k0 + gcol, lA + flat);
      GLD16(B + (size_t)(N0 + row) * 2048 + k0 + gcol, lB + flat);
    }
    __syncthreads();
    const int sw = lq & 7;
#pragma unroll
    for (int ks8 = 0; ks8 < 8; ks8 += 4) {        // ks = ks8*8 in {0,32}
      short8 af[4], bf[4];
#pragma unroll
      for (int t = 0; t < 4; ++t)
        af[t] = *(const short8*)&lA[(wm * 64 + t * 16 + lq) * 64 + (((quad + ks8) ^ sw) << 3)];
#pragma unroll
      for (int t = 0; t < 4; ++t)
        bf[t] = *(const short8*)&lB[(wn * 64 + t * 16 + lq) * 64 + (((quad + ks8) ^ sw) << 3)];
#pragma unroll
      for (int i = 0; i < 4; ++i)
#pragma unroll
        for (int j = 0; j < 4; ++j)
          acc[i][j] = __builtin_amdgcn_mfma_f32_16x16x32_bf16(af[i], bf[j], acc[i][j], 0, 0, 0);
    }
  }

  // epilogue: C/D layout col=lane&15, row=quad*4+reg
#pragma unroll
  for (int i = 0; i < 4; ++i)
#pragma unroll
    for (int j = 0; j < 4; ++j)
#pragma unroll
      for (int r = 0; r < 4; ++r) {
        const int m = M0 + wm * 64 + i * 16 + quad * 4 + r;
        const int n = N0 + wn * 64 + j * 16 + lq;
        if (mode == 0) {
          Cf[(size_t)m * 2048 + n] = acc[i][j][r];
        } else {
          const int bh = ((m >> 10) << 5) | (n >> 6);  // b*32 + head
          size_t addr;
          if (mode == 1) addr = ((size_t)bh * 1024 + (m & 1023)) * 64 + (n & 63);
          else           addr = ((size_t)bh * 64 + (n & 63)) * 1024 + (m & 1023);
          Cb[addr] = f2bf(acc[i][j][r] * cscale);
        }
      }
}

__global__ __launch_bounds__(256, 3) void gemm_qkv(
    const u16* __restrict__ H,
    const u16* __restrict__ Wq, const u16* __restrict__ Wk, const u16* __restrict__ Wv,
    u16* __restrict__ q, u16* __restrict__ k, u16* __restrict__ vt) {
  __shared__ __align__(16) u16 lA[128 * 64];
  __shared__ __align__(16) u16 lB[128 * 64];
  const int M0 = blockIdx.x * 128;
  const int sel = blockIdx.y >> 4;        // 0:Q 1:K 2:V
  const int N0 = (blockIdx.y & 15) * 128;
  const u16* B = (sel == 0) ? Wq : (sel == 1) ? Wk : Wv;
  u16* C = (sel == 0) ? q : (sel == 1) ? k : vt;
  gemm_core(H, B, C, nullptr, M0, N0, (sel == 2) ? 2 : 1,
            (sel == 0) ? 0.125f : 1.f, lA, lB);
}

__global__ __launch_bounds__(256, 3) void gemm_out(
    const u16* __restrict__ A, const u16* __restrict__ W, float* __restrict__ C) {
  __shared__ __align__(16) u16 lA[128 * 64];
  __shared__ __align__(16) u16 lB[128 * 64];
  gemm_core(A, W, nullptr, C, blockIdx.x * 128, blockIdx.y * 128, 0, 1.f, lA, lB);
}

// ---------------------------------------------------------------------------
// Stick-breaking attention, multiplicative form, transposed z, KEY-SPLIT:
//   p = sigmoid(z), att[i,j] = p(i,j) * prod_{j<k<i} (1 - p(i,k))
// Associativity over key ranges: O = O_A + tot_A * O_B  (A = keys nearest
// diagonal). Each q-tile's key range is split across 2 waves of the block;
// partials combine through an LDS f32 buffer + one __syncthreads.
// -> max 9 tiles/wave (was 17), 8192 waves (was 4096): TLP not ILP (R7's
// register-prefetch spilled to scratch and regressed).
// ---------------------------------------------------------------------------
#define PSTR 72   // P slab row stride in u16 (64 + 8 pad)
#define PBUF (16 * PSTR)
#define CSTR 68   // combine buffer row stride in f32 (64 + 4 pad)

__device__ __forceinline__ void sba_tile_body(
    int j0, int q0, int lq, int quad, bool masked,
    const u16* __restrict__ kb0, const u16* __restrict__ vb, u16* pw,
    const short8& qf0, const short8& qf1,
    floatx4 (&o)[4], float& carry) {
  // K A-frags: A[m=key 16c+lq][k=d chunk]
  short8 kf0[4], kf1[4];
#pragma unroll
  for (int c = 0; c < 4; ++c) {
    const u16* kr = &kb0[(size_t)(j0 + 16 * c + lq) * 64 + quad * 8];
    kf0[c] = *(const short8*)kr;
    kf1[c] = *(const short8*)(kr + 32);
  }
  floatx4 zc[4];
#pragma unroll
  for (int c = 0; c < 4; ++c) {
    floatx4 z = (floatx4)0.f;
    z = __builtin_amdgcn_mfma_f32_16x16x32_bf16(kf0[c], qf0, z, 0, 0, 0);
    z = __builtin_amdgcn_mfma_f32_16x16x32_bf16(kf1[c], qf1, z, 0, 0, 0);
    zc[c] = z;
  }
  // V A-frags (consumed after the LDS round-trip)
  short8 vfA[4], vfB[4];
#pragma unroll
  for (int tt = 0; tt < 4; ++tt) {
    const u16* vr = &vb[(size_t)(tt * 16 + lq) * 1024 + j0 + quad * 8];
    vfA[tt] = *(const short8*)vr;
    vfB[tt] = *(const short8*)(vr + 32);
  }
  // per-chunk: pe_r = p_r * (in-quad g-suffix), qt = quad product of g
  float pe0[4], pe1[4], pe2[4], pe3[4], qt[4];
#pragma unroll
  for (int c = 0; c < 4; ++c) {
    float p[4], g[4];
#pragma unroll
    for (int r = 0; r < 4; ++r) {
      const float z = zc[c][r];
      const float e = __expf(-z);
      float pp = __builtin_amdgcn_rcpf(1.f + e);   // sigmoid
      float gg = e * pp;                            // 1 - sigmoid
      if (masked) {
        const bool valid = (j0 + 16 * c + quad * 4 + r) < (q0 + lq);
        gg = valid ? gg : 1.f;
        pp = valid ? pp : 0.f;
      }
      p[r] = pp; g[r] = gg;
    }
    const float er2 = g[3];
    const float er1 = er2 * g[2];
    const float er0 = er1 * g[1];
    qt[c] = er0 * g[0];
    pe0[c] = p[0] * er0; pe1[c] = p[1] * er1; pe2[c] = p[2] * er2; pe3[c] = p[3];
  }
  // 16 independent cross-quad gathers (no chained scan)
  float s0[4], s1[4], s2[4], s3[4];
#pragma unroll
  for (int c = 0; c < 4; ++c) {
    s0[c] = __shfl(qt[c], lq);
    s1[c] = __shfl(qt[c], lq + 16);
    s2[c] = __shfl(qt[c], lq + 32);
    s3[c] = __shfl(qt[c], lq + 48);
  }
  float tot[4], Qs[4];
#pragma unroll
  for (int c = 0; c < 4; ++c) {
    const float a = (quad < 1) ? s1[c] : 1.f;
    const float b = (quad < 2) ? s2[c] : 1.f;
    const float d = (quad < 3) ? s3[c] : 1.f;
    Qs[c] = a * b * d;                       // exclusive quad-suffix
    tot[c] = s0[c] * s1[c] * s2[c] * s3[c];  // chunk total
  }
  const float suf2 = tot[3];
  const float suf1 = tot[3] * tot[2];
  const float suf0 = suf1 * tot[1];
  const float tile_tot = suf0 * tot[0];
  const float QF[4] = {Qs[0] * suf0 * carry, Qs[1] * suf1 * carry,
                       Qs[2] * suf2 * carry, Qs[3] * carry};
#pragma unroll
  for (int c = 0; c < 4; ++c) {
    ushort4 pk;
    pk.x = f2bf(pe0[c] * QF[c]);
    pk.y = f2bf(pe1[c] * QF[c]);
    pk.z = f2bf(pe2[c] * QF[c]);
    pk.w = f2bf(pe3[c] * QF[c]);
    *(ushort4*)&pw[lq * PSTR + c * 16 + quad * 4] = pk;  // [query][key]
  }
  carry *= tile_tot;
  __asm__ volatile("s_waitcnt lgkmcnt(0)" ::: "memory");  // P visible to own wave
  const short8 pA = *(const short8*)&pw[lq * PSTR + quad * 8];
  const short8 pB = *(const short8*)&pw[lq * PSTR + 32 + quad * 8];
#pragma unroll
  for (int tt = 0; tt < 4; ++tt) {
    o[tt] = __builtin_amdgcn_mfma_f32_16x16x32_bf16(vfA[tt], pA, o[tt], 0, 0, 0);
    o[tt] = __builtin_amdgcn_mfma_f32_16x16x32_bf16(vfB[tt], pB, o[tt], 0, 0, 0);
  }
  // DS in-order per wave: next tile's ds_write cannot pass the reads above.
}

__global__ __launch_bounds__(256, 6) void sba_attn(
    const u16* __restrict__ Q, const u16* __restrict__ Km,
    const u16* __restrict__ Vt, u16* __restrict__ AO) {
  __shared__ __align__(16) u16 lP[4][PBUF];          // per-wave P slab
  __shared__ __align__(16) float cbuf[2][16 * CSTR]; // per-pair combine buffer
  const int tid = threadIdx.x;
  const int lane = tid & 63;
  const int wave = tid >> 6;
  const int lq = lane & 15, quad = lane >> 4;
  const int pl = wave >> 1;     // pair slot in block (0,1)
  const int half = wave & 1;    // 0 = A (diagonal side), 1 = B (low keys)

  // 2048 blocks: 64 bh x 32 q-tile-pairs, XCD-affine
  const int blk = blockIdx.x;
  const int xcd = blk & 7, y = blk >> 3;        // y: 0..255
  const int bh = xcd + 8 * (y >> 5);
  const int p = y & 31;                         // pair index
  const int t = pl ? (63 - p) : p;              // q-tile of this wave pair
  const int q0 = t << 4;

  const int nt = (q0 >> 6) + 1;                 // 64-key tiles in [0, q0]
  const int nA = (nt + 1) >> 1;
  const int nB = nt - nA;
  const int j0d = q0 & ~63;

  // Q B-frags (pre-scaled by 1/8 in gemm_qkv)
  const u16* qb = Q + ((size_t)bh * 1024 + q0) * 64;
  const short8 qf0 = *(const short8*)&qb[lq * 64 + quad * 8];
  const short8 qf1 = *(const short8*)&qb[lq * 64 + 32 + quad * 8];

  const u16* kb0 = Km + (size_t)bh * 65536;
  const u16* vb  = Vt + (size_t)bh * 65536;

  floatx4 o[4];
#pragma unroll
  for (int tt = 0; tt < 4; ++tt) o[tt] = (floatx4)0.f;
  float carry = 1.f;
  u16* pw = &lP[wave][0];

  if (half == 0) {
    int j0 = j0d;
    sba_tile_body(j0, q0, lq, quad, true, kb0, vb, pw, qf0, qf1, o, carry);
    j0 -= 64;
    for (int it = 1; it < nA; ++it, j0 -= 64)
      sba_tile_body(j0, q0, lq, quad, false, kb0, vb, pw, qf0, qf1, o, carry);
  } else {
    int j0 = j0d - 64 * nA;
    for (int it = 0; it < nB; ++it, j0 -= 64)
      sba_tile_body(j0, q0, lq, quad, false, kb0, vb, pw, qf0, qf1, o, carry);
    // publish partial O_B (f32) for the A-wave
    float* cb = &cbuf[pl][0];
#pragma unroll
    for (int tt = 0; tt < 4; ++tt)
      *(floatx4*)&cb[lq * CSTR + tt * 16 + quad * 4] = o[tt];
  }
  __syncthreads();
  if (half != 0) return;

  // combine: O = O_A + tot_A * O_B   (carry == tot_A after A's loop)
  const float* cb = &cbuf[pl][0];
#pragma unroll
  for (int tt = 0; tt < 4; ++tt) {
    const floatx4 ob = *(const floatx4*)&cb[lq * CSTR + tt * 16 + quad * 4];
#pragma unroll
    for (int r = 0; r < 4; ++r)
      o[tt][r] = fmaf(carry, ob[r], o[tt][r]);
  }

  // O^T (d=tt*16+quad*4+r, query=lq) -> LDS [query][d] -> coalesced 16B stores
#pragma unroll
  for (int tt = 0; tt < 4; ++tt) {
    ushort4 pk;
    pk.x = f2bf(o[tt][0]); pk.y = f2bf(o[tt][1]);
    pk.z = f2bf(o[tt][2]); pk.w = f2bf(o[tt][3]);
    *(ushort4*)&pw[lq * PSTR + tt * 16 + quad * 4] = pk;
  }
  __asm__ volatile("s_waitcnt lgkmcnt(0)" ::: "memory");
  const int b = bh >> 5, hd = bh & 31;
#pragma unroll
  for (int ps = 0; ps < 2; ++ps) {
    const int row = lane >> 2;
    const int colu = ((lane & 3) + 4 * ps) * 8;
    const short8 val = *(const short8*)&pw[row * PSTR + colu];
    *(short8*)&AO[((size_t)b * 1024 + q0 + row) * 2048 + hd * 64 + colu] = val;
  }
}

extern "C" void kernel_launch(void* const* d_in, const int* in_sizes, int n_in,
                              void* d_out, int out_size, void* d_ws, size_t ws_size,
                              hipStream_t stream) {
  const float* H  = (const float*)d_in[0];
  const float* Wq = (const float*)d_in[1];
  const float* Wk = (const float*)d_in[2];
  const float* Wv = (const float*)d_in[3];
  const float* Wo = (const float*)d_in[4];

  u16* ws = (u16*)d_ws;
  u16* Hb  = ws;                  // [2048,2048] 8MB  (reused as ao after gemm_qkv)
  u16* Wqb = ws + 1 * 4194304;
  u16* Wkb = ws + 2 * 4194304;
  u16* Wvb = ws + 3 * 4194304;
  u16* Wob = ws + 4 * 4194304;
  u16* q   = ws + 5 * 4194304;    // [64,1024,64], pre-scaled by 1/8
  u16* k   = ws + 6 * 4194304;
  u16* vt  = ws + 7 * 4194304;    // [64,64,1024]
  u16* ao  = Hb;                  // alias: H consumed by gemm_qkv before sba_attn writes

  dim3 gc(4096, 5);
  cvt_all<<<gc, 256, 0, stream>>>(H, Wq, Wk, Wv, Wo, ws);

  dim3 gq(16, 48);
  gemm_qkv<<<gq, 256, 0, stream>>>(Hb, Wqb, Wkb, Wvb, q, k, vt);
  sba_attn<<<2048, 256, 0, stream>>>(q, k, vt, ao);
  dim3 go(16, 16);
  gemm_out<<<go, 256, 0, stream>>>(ao, Wob, (float*)d_out);
}

// Round 9
// 282.007 us; speedup vs baseline: 1.1519x; 1.0528x over previous
//
#include <hip/hip_runtime.h>
#include <math.h>

typedef unsigned short u16;
typedef __attribute__((ext_vector_type(8))) short short8;   // 8 bf16 = 4 VGPRs
typedef __attribute__((ext_vector_type(4))) float floatx4;  // MFMA 16x16 C/D

// fp32 -> bf16 round-to-nearest-even
__device__ __forceinline__ u16 f2bf(float f) {
  union { float f; unsigned u; } v; v.f = f;
  unsigned r = (v.u + 0x7FFFu + ((v.u >> 16) & 1u)) >> 16;
  return (u16)r;
}

// async global->LDS, 16B per lane; LDS dest must be wave-uniform base + lane*16
#define GLD16(gp, lp) __builtin_amdgcn_global_load_lds(                      \
    (__attribute__((address_space(1))) void*)(gp),                           \
    (__attribute__((address_space(3))) void*)(lp), 16, 0, 0)

// ---------------------------------------------------------------------------
// f32 -> bf16 conversion: 5 tensors of 4194304 elements each, contiguous dst.
// ---------------------------------------------------------------------------
__global__ __launch_bounds__(256) void cvt_all(
    const float* __restrict__ H, const float* __restrict__ Wq,
    const float* __restrict__ Wk, const float* __restrict__ Wv,
    const float* __restrict__ Wo, u16* __restrict__ dst) {
  const float* srcs[5] = {H, Wq, Wk, Wv, Wo};
  const int sel = blockIdx.y;
  const float* s = srcs[sel];
  u16* d = dst + (size_t)sel * 4194304;
  const int idx = (blockIdx.x * 256 + threadIdx.x) * 4;
  const float4 v = *(const float4*)(s + idx);
  ushort4 o;
  o.x = f2bf(v.x); o.y = f2bf(v.y); o.z = f2bf(v.z); o.w = f2bf(v.w);
  *(ushort4*)(d + idx) = o;
}

// ---------------------------------------------------------------------------
// GEMM core: C[m,n] = sum_k A[m,k] * B[n,k]  (B^T layout, all dims 2048)
// 128x128 tile, BK=64, 4 waves each computing 64x64 (4x4 MFMA tiles).
// XOR column-chunk swizzle breaks the 16-way LDS bank conflict (R6 win).
// ---------------------------------------------------------------------------
__device__ __forceinline__ void gemm_core(const u16* __restrict__ A,
                                          const u16* __restrict__ B,
                                          u16* __restrict__ Cb,
                                          float* __restrict__ Cf,
                                          int M0, int N0, int mode, float cscale,
                                          u16* lA, u16* lB) {
  const int tid = threadIdx.x;
  const int lane = tid & 63;
  const int wave = tid >> 6;
  const int lq = lane & 15, quad = lane >> 4;
  const int wm = wave & 1, wn = wave >> 1;

  floatx4 acc[4][4];
#pragma unroll
  for (int i = 0; i < 4; ++i)
#pragma unroll
    for (int j = 0; j < 4; ++j) acc[i][j] = (floatx4)0.f;

  const int srow = tid >> 3;        // 0..31
  const int cc = tid & 7;           // column chunk 0..7

  for (int k0 = 0; k0 < 2048; k0 += 64) {
    __syncthreads();
#pragma unroll
    for (int r = 0; r < 4; ++r) {
      const int row = r * 32 + srow;
      const int gcol = ((cc ^ (row & 7)) << 3);   // swizzled global chunk
      const int flat = row * 64 + (cc << 3);      // contiguous LDS dest
      GLD16(A + (size_t)(M0 + row) * 2048 + k0 + gcol, lA + flat);
      GLD16(B + (size_t)(N0 + row) * 2048 + k0 + gcol, lB + flat);
    }
    __syncthreads();
    const int sw = lq & 7;
#pragma unroll
    for (int ks8 = 0; ks8 < 8; ks8 += 4) {        // ks = ks8*8 in {0,32}
      short8 af[4], bf[4];
#pragma unroll
      for (int t = 0; t < 4; ++t)
        af[t] = *(const short8*)&lA[(wm * 64 + t * 16 + lq) * 64 + (((quad + ks8) ^ sw) << 3)];
#pragma unroll
      for (int t = 0; t < 4; ++t)
        bf[t] = *(const short8*)&lB[(wn * 64 + t * 16 + lq) * 64 + (((quad + ks8) ^ sw) << 3)];
#pragma unroll
      for (int i = 0; i < 4; ++i)
#pragma unroll
        for (int j = 0; j < 4; ++j)
          acc[i][j] = __builtin_amdgcn_mfma_f32_16x16x32_bf16(af[i], bf[j], acc[i][j], 0, 0, 0);
    }
  }

  // epilogue: C/D layout col=lane&15, row=quad*4+reg
#pragma unroll
  for (int i = 0; i < 4; ++i)
#pragma unroll
    for (int j = 0; j < 4; ++j)
#pragma unroll
      for (int r = 0; r < 4; ++r) {
        const int m = M0 + wm * 64 + i * 16 + quad * 4 + r;
        const int n = N0 + wn * 64 + j * 16 + lq;
        if (mode == 0) {
          Cf[(size_t)m * 2048 + n] = acc[i][j][r];
        } else {
          const int bh = ((m >> 10) << 5) | (n >> 6);  // b*32 + head
          size_t addr;
          if (mode == 1) addr = ((size_t)bh * 1024 + (m & 1023)) * 64 + (n & 63);
          else           addr = ((size_t)bh * 64 + (n & 63)) * 1024 + (m & 1023);
          Cb[addr] = f2bf(acc[i][j][r] * cscale);
        }
      }
}

__global__ __launch_bounds__(256, 3) void gemm_qkv(
    const u16* __restrict__ H,
    const u16* __restrict__ Wq, const u16* __restrict__ Wk, const u16* __restrict__ Wv,
    u16* __restrict__ q, u16* __restrict__ k, u16* __restrict__ vt) {
  __shared__ __align__(16) u16 lA[128 * 64];
  __shared__ __align__(16) u16 lB[128 * 64];
  const int M0 = blockIdx.x * 128;
  const int sel = blockIdx.y >> 4;        // 0:Q 1:K 2:V
  const int N0 = (blockIdx.y & 15) * 128;
  const u16* B = (sel == 0) ? Wq : (sel == 1) ? Wk : Wv;
  u16* C = (sel == 0) ? q : (sel == 1) ? k : vt;
  gemm_core(H, B, C, nullptr, M0, N0, (sel == 2) ? 2 : 1,
            (sel == 0) ? 0.125f : 1.f, lA, lB);
}

__global__ __launch_bounds__(256, 3) void gemm_out(
    const u16* __restrict__ A, const u16* __restrict__ W, float* __restrict__ C) {
  __shared__ __align__(16) u16 lA[128 * 64];
  __shared__ __align__(16) u16 lB[128 * 64];
  gemm_core(A, W, nullptr, C, blockIdx.x * 128, blockIdx.y * 128, 0, 1.f, lA, lB);
}

// ---------------------------------------------------------------------------
// Stick-breaking attention, multiplicative form, transposed z, 4-WAY KEY-SPLIT
// PER BLOCK:  p = sigmoid(z), att[i,j] = p(i,j) * prod_{j<k<i} (1 - p(i,k))
// One q-tile per block; its key range is split into 4 contiguous chunks over
// the block's 4 waves (<=1 tile skew -> the combine barrier is nearly free;
// this fixes R8's idle-at-barrier imbalance). Combine tree:
//   O = O0 + T0*O1 + T0*T1*O2 + T0*T1*T2*O3   (T_w = range product)
// through an f32 LDS buffer; waves 1-3 publish + exit, wave 0 stores.
// ---------------------------------------------------------------------------
#define PSTR 72   // P slab row stride in u16 (64 + 8 pad)
#define PBUF (16 * PSTR)
#define CSTR 68   // combine buffer row stride in f32 (64 + 4 pad)

__device__ __forceinline__ void sba_tile_body(
    int j0, int q0, int lq, int quad, bool masked,
    const u16* __restrict__ kb0, const u16* __restrict__ vb, u16* pw,
    const short8& qf0, const short8& qf1,
    floatx4 (&o)[4], float& carry) {
  // K A-frags: A[m=key 16c+lq][k=d chunk]
  short8 kf0[4], kf1[4];
#pragma unroll
  for (int c = 0; c < 4; ++c) {
    const u16* kr = &kb0[(size_t)(j0 + 16 * c + lq) * 64 + quad * 8];
    kf0[c] = *(const short8*)kr;
    kf1[c] = *(const short8*)(kr + 32);
  }
  floatx4 zc[4];
#pragma unroll
  for (int c = 0; c < 4; ++c) {
    floatx4 z = (floatx4)0.f;
    z = __builtin_amdgcn_mfma_f32_16x16x32_bf16(kf0[c], qf0, z, 0, 0, 0);
    z = __builtin_amdgcn_mfma_f32_16x16x32_bf16(kf1[c], qf1, z, 0, 0, 0);
    zc[c] = z;
  }
  // V A-frags (consumed after the LDS round-trip)
  short8 vfA[4], vfB[4];
#pragma unroll
  for (int tt = 0; tt < 4; ++tt) {
    const u16* vr = &vb[(size_t)(tt * 16 + lq) * 1024 + j0 + quad * 8];
    vfA[tt] = *(const short8*)vr;
    vfB[tt] = *(const short8*)(vr + 32);
  }
  // per-chunk: pe_r = p_r * (in-quad g-suffix), qt = quad product of g
  float pe0[4], pe1[4], pe2[4], pe3[4], qt[4];
#pragma unroll
  for (int c = 0; c < 4; ++c) {
    float p[4], g[4];
#pragma unroll
    for (int r = 0; r < 4; ++r) {
      const float z = zc[c][r];
      const float e = __expf(-z);
      float pp = __builtin_amdgcn_rcpf(1.f + e);   // sigmoid
      float gg = e * pp;                            // 1 - sigmoid
      if (masked) {
        const bool valid = (j0 + 16 * c + quad * 4 + r) < (q0 + lq);
        gg = valid ? gg : 1.f;
        pp = valid ? pp : 0.f;
      }
      p[r] = pp; g[r] = gg;
    }
    const float er2 = g[3];
    const float er1 = er2 * g[2];
    const float er0 = er1 * g[1];
    qt[c] = er0 * g[0];
    pe0[c] = p[0] * er0; pe1[c] = p[1] * er1; pe2[c] = p[2] * er2; pe3[c] = p[3];
  }
  // 16 independent cross-quad gathers (no chained scan)
  float s0[4], s1[4], s2[4], s3[4];
#pragma unroll
  for (int c = 0; c < 4; ++c) {
    s0[c] = __shfl(qt[c], lq);
    s1[c] = __shfl(qt[c], lq + 16);
    s2[c] = __shfl(qt[c], lq + 32);
    s3[c] = __shfl(qt[c], lq + 48);
  }
  float tot[4], Qs[4];
#pragma unroll
  for (int c = 0; c < 4; ++c) {
    const float a = (quad < 1) ? s1[c] : 1.f;
    const float b = (quad < 2) ? s2[c] : 1.f;
    const float d = (quad < 3) ? s3[c] : 1.f;
    Qs[c] = a * b * d;                       // exclusive quad-suffix
    tot[c] = s0[c] * s1[c] * s2[c] * s3[c];  // chunk total
  }
  const float suf2 = tot[3];
  const float suf1 = tot[3] * tot[2];
  const float suf0 = suf1 * tot[1];
  const float tile_tot = suf0 * tot[0];
  const float QF[4] = {Qs[0] * suf0 * carry, Qs[1] * suf1 * carry,
                       Qs[2] * suf2 * carry, Qs[3] * carry};
#pragma unroll
  for (int c = 0; c < 4; ++c) {
    ushort4 pk;
    pk.x = f2bf(pe0[c] * QF[c]);
    pk.y = f2bf(pe1[c] * QF[c]);
    pk.z = f2bf(pe2[c] * QF[c]);
    pk.w = f2bf(pe3[c] * QF[c]);
    *(ushort4*)&pw[lq * PSTR + c * 16 + quad * 4] = pk;  // [query][key]
  }
  carry *= tile_tot;
  __asm__ volatile("s_waitcnt lgkmcnt(0)" ::: "memory");  // P visible to own wave
  const short8 pA = *(const short8*)&pw[lq * PSTR + quad * 8];
  const short8 pB = *(const short8*)&pw[lq * PSTR + 32 + quad * 8];
#pragma unroll
  for (int tt = 0; tt < 4; ++tt) {
    o[tt] = __builtin_amdgcn_mfma_f32_16x16x32_bf16(vfA[tt], pA, o[tt], 0, 0, 0);
    o[tt] = __builtin_amdgcn_mfma_f32_16x16x32_bf16(vfB[tt], pB, o[tt], 0, 0, 0);
  }
  // DS in-order per wave: next tile's ds_write cannot pass the reads above.
}

__global__ __launch_bounds__(256, 4) void sba_attn(
    const u16* __restrict__ Q, const u16* __restrict__ Km,
    const u16* __restrict__ Vt, u16* __restrict__ AO) {
  __shared__ __align__(16) u16 lP[4][PBUF];           // per-wave P slab
  __shared__ __align__(16) float cbuf[3][16 * CSTR];  // waves 1..3 partial O
  __shared__ float ctot[3][16];                       // waves 1..2 range totals
  const int tid = threadIdx.x;
  const int lane = tid & 63;
  const int wave = tid >> 6;
  const int lq = lane & 15, quad = lane >> 4;

  // 4096 blocks = 64 bh x 64 q-tiles; same-bh blocks share an XCD
  const int blk = blockIdx.x;
  const int xcd = blk & 7, grp = blk >> 3;      // grp: 0..511
  const int bh = xcd + 8 * (grp & 7);
  const int t = grp >> 3;                       // q-tile 0..63
  const int q0 = t << 4;

  // key-range split: nt tiles among 4 waves, contiguous from the diagonal
  const int nt = (q0 >> 6) + 1;
  const int base = nt >> 2, rem = nt & 3;
  const int cnt = base + (wave < rem ? 1 : 0);
  const int s = wave * base + ((wave < rem) ? wave : rem);

  // Q B-frags (pre-scaled by 1/8 in gemm_qkv)
  const u16* qb = Q + ((size_t)bh * 1024 + q0) * 64;
  const short8 qf0 = *(const short8*)&qb[lq * 64 + quad * 8];
  const short8 qf1 = *(const short8*)&qb[lq * 64 + 32 + quad * 8];

  const u16* kb0 = Km + (size_t)bh * 65536;
  const u16* vb  = Vt + (size_t)bh * 65536;

  floatx4 o[4];
#pragma unroll
  for (int tt = 0; tt < 4; ++tt) o[tt] = (floatx4)0.f;
  float carry = 1.f;
  u16* pw = &lP[wave][0];

  int j0 = (q0 & ~63) - 64 * s;
  for (int it = 0; it < cnt; ++it, j0 -= 64)
    sba_tile_body(j0, q0, lq, quad, (wave == 0 && it == 0),
                  kb0, vb, pw, qf0, qf1, o, carry);

  if (wave != 0) {
    float* cb = &cbuf[wave - 1][0];
#pragma unroll
    for (int tt = 0; tt < 4; ++tt)
      *(floatx4*)&cb[lq * CSTR + tt * 16 + quad * 4] = o[tt];
    if (wave < 3 && quad == 0) ctot[wave - 1][lq] = carry;
  }
  __syncthreads();
  if (wave != 0) return;

  // combine tree (wave 0): O = O0 + T0*O1 + T0*T1*O2 + T0*T1*T2*O3
  float T = carry;
#pragma unroll
  for (int w = 1; w < 4; ++w) {
    const float* cb = &cbuf[w - 1][0];
#pragma unroll
    for (int tt = 0; tt < 4; ++tt) {
      const floatx4 ob = *(const floatx4*)&cb[lq * CSTR + tt * 16 + quad * 4];
#pragma unroll
      for (int r = 0; r < 4; ++r)
        o[tt][r] = fmaf(T, ob[r], o[tt][r]);
    }
    if (w < 3) T *= ctot[w - 1][lq];
  }

  // O^T (d=tt*16+quad*4+r, query=lq) -> LDS [query][d] -> coalesced 16B stores
#pragma unroll
  for (int tt = 0; tt < 4; ++tt) {
    ushort4 pk;
    pk.x = f2bf(o[tt][0]); pk.y = f2bf(o[tt][1]);
    pk.z = f2bf(o[tt][2]); pk.w = f2bf(o[tt][3]);
    *(ushort4*)&pw[lq * PSTR + tt * 16 + quad * 4] = pk;
  }
  __asm__ volatile("s_waitcnt lgkmcnt(0)" ::: "memory");
  const int b = bh >> 5, hd = bh & 31;
#pragma unroll
  for (int ps = 0; ps < 2; ++ps) {
    const int row = lane >> 2;
    const int colu = ((lane & 3) + 4 * ps) * 8;
    const short8 val = *(const short8*)&pw[row * PSTR + colu];
    *(short8*)&AO[((size_t)b * 1024 + q0 + row) * 2048 + hd * 64 + colu] = val;
  }
}

extern "C" void kernel_launch(void* const* d_in, const int* in_sizes, int n_in,
                              void* d_out, int out_size, void* d_ws, size_t ws_size,
                              hipStream_t stream) {
  const float* H  = (const float*)d_in[0];
  const float* Wq = (const float*)d_in[1];
  const float* Wk = (const float*)d_in[2];
  const float* Wv = (const float*)d_in[3];
  const float* Wo = (const float*)d_in[4];

  u16* ws = (u16*)d_ws;
  u16* Hb  = ws;                  // [2048,2048] 8MB  (reused as ao after gemm_qkv)
  u16* Wqb = ws + 1 * 4194304;
  u16* Wkb = ws + 2 * 4194304;
  u16* Wvb = ws + 3 * 4194304;
  u16* Wob = ws + 4 * 4194304;
  u16* q   = ws + 5 * 4194304;    // [64,1024,64], pre-scaled by 1/8
  u16* k   = ws + 6 * 4194304;
  u16* vt  = ws + 7 * 4194304;    // [64,64,1024]
  u16* ao  = Hb;                  // alias: H consumed by gemm_qkv before sba_attn writes

  dim3 gc(4096, 5);
  cvt_all<<<gc, 256, 0, stream>>>(H, Wq, Wk, Wv, Wo, ws);

  dim3 gq(16, 48);
  gemm_qkv<<<gq, 256, 0, stream>>>(Hb, Wqb, Wkb, Wvb, q, k, vt);
  sba_attn<<<4096, 256, 0, stream>>>(q, k, vt, ao);
  dim3 go(16, 16);
  gemm_out<<<go, 256, 0, stream>>>(ao, Wob, (float*)d_out);
}